// Round 11
// baseline (148.476 us; speedup 1.0000x reference)
//
#include <hip/hip_runtime.h>

// MPS tensor-train classifier, B=16384, D=784, BOND=5, OUT=10.
//
// Round-14 = round-13 (quarter-split, dual-row, SGPR coefficients) made
// fault-proof after the r13 container crash (possible cause: 4.1 MB ws
// stash vs unknown ws_size -> OOB writes).
//   1. vL/wR stash -> out (163,840 floats, exact fit; r12-proven pattern).
//   2. ws only holds pk (160 KB) + M1/M2 (3.3 MB); host guards ws_size and
//      falls back to the PROVEN r12 half-split kernel (156 KB ws) if small.
//   3. seg1/2 fold rewritten in-place (foldM) to kill the TA/TB register
//      doubling (~110 live floats -> ~60).
// Quarter geometry: 512 blocks x 512 thr (2 blocks/CU, 4 waves/SIMD, 2x
// memory parallelism vs r12's 1 block/CU which was HBM-amplification-bound:
// FETCH 174 MB = 3.4x of x, 174/3.0TB/s = 58us = dur).
//   seg0: wave0 = left boundary + pairs 0..12, fold asc -> vL (out).
//         waves1-7: 12-pair chains, pairs 13..96.
//   seg1: wave0 = chain 97..110 + fold asc -> M1 (ws). waves1-7: 111..194.
//   seg2: wave0 = chain 195..208 + fold asc -> M2 (ws). waves1-7: 209..292.
//   seg3: waves1-7: 293..376; wave0 = right boundary + pairs 389..377 desc
//         (transposed storage), fold desc -> wR (out).
//   finish_dot_q: res = (vL@M1@M2).wR -> ws[0..Bn) (pk dead).
//   finish_out: out = res*fc_w + fc_b.
//
// pk layout (100 floats/pair), q = 0..3 (coeff of 1, xa, xb, xa*xb):
//   rows: q*20+l*4+r (quad s4[q*5+l]); col4: 80+l*4+q (s4[20+l], l-major);
//   (4,4): 96+q (s4[24]).

typedef float v4f __attribute__((ext_vector_type(4)));
typedef float v2f __attribute__((ext_vector_type(2)));

constexpr int Bn     = 16384;
constexpr int Dn     = 784;
constexpr int NOUT   = 10;
constexpr int NPAIR  = 390;
constexpr int PAIR_F = 100;
constexpr int WROFF  = Bn * 5;          // wR stash offset (floats) in out
// ws float offsets (quarter path)
constexpr int PK_F   = 40960;           // pk region (39000 used, padded)
constexpr int M_OFF  = PK_F;            // M1,M2: (k*Bn + row)*25

__device__ __forceinline__ v4f splat4(float x) { v4f v = {x, x, x, x}; return v; }
__device__ __forceinline__ v4f fma4(v4f a, v4f b, v4f c) {
    return __builtin_elementwise_fma(a, b, c);
}

struct Frag { v4f r[5]; float c4[5]; };          // 5x5 running product
struct CMat { v4f row[5]; v4f c4v; float c44; }; // 5x5 pair matrix

__device__ __forceinline__ void build_C(CMat& C, const float* __restrict__ s,
                                        v2f xc) {
    const float xa = xc[0], xb = xc[1], xab = xa * xb;
    const v4f va = splat4(xa), vb = splat4(xb), vp = splat4(xab);
    const v4f* s4 = (const v4f*)s;
#pragma unroll
    for (int l = 0; l < 5; ++l)
        C.row[l] = fma4(vp, s4[15 + l], fma4(vb, s4[10 + l], fma4(va, s4[5 + l], s4[l])));
#pragma unroll
    for (int l = 0; l < 4; ++l) {
        v4f cq = s4[20 + l];
        C.c4v[l] = fmaf(xab, cq[3], fmaf(xb, cq[2], fmaf(xa, cq[1], cq[0])));
    }
    {
        v4f cq = s4[24];
        C.c44 = fmaf(xab, cq[3], fmaf(xb, cq[2], fmaf(xa, cq[1], cq[0])));
    }
}

__device__ __forceinline__ void matmulIP(Frag& M, const CMat& C) {
#pragma unroll
    for (int i = 0; i < 5; ++i) {
        v4f acc  = splat4(M.r[i][0]) * C.row[0];
        float a4 = M.r[i][0] * C.c4v[0];
#pragma unroll
        for (int l = 1; l < 4; ++l) {
            acc = fma4(splat4(M.r[i][l]), C.row[l], acc);
            a4  = fmaf(M.r[i][l], C.c4v[l], a4);
        }
        acc = fma4(splat4(M.c4[i]), C.row[4], acc);
        a4  = fmaf(M.c4[i], C.c44, a4);
        M.r[i] = acc; M.c4[i] = a4;
    }
}

__device__ __forceinline__ void vecstepC(v4f& cv, float& c4, const CMat& C) {
    v4f acc  = splat4(cv[0]) * C.row[0];
    float a4 = cv[0] * C.c4v[0];
#pragma unroll
    for (int l = 1; l < 4; ++l) {
        acc = fma4(splat4(cv[l]), C.row[l], acc);
        a4  = fmaf(cv[l], C.c4v[l], a4);
    }
    acc = fma4(splat4(c4), C.row[4], acc);
    a4  = fmaf(c4, C.c44, a4);
    cv = acc; c4 = a4;
}

// dual-row matrix chain over n pairs starting at p0 (uniform)
__device__ __forceinline__ void mat_chain(Frag& MA, Frag& MB, int p0, int n,
                                          const float* __restrict__ pk,
                                          const v2f* __restrict__ xA2,
                                          const v2f* __restrict__ xB2) {
    v2f xA = xA2[p0 + 1], xB = xB2[p0 + 1];
#pragma unroll 1
    for (int j = 0; j < n; ++j) {
        const float* s = pk + (size_t)(p0 + j) * PAIR_F;   // uniform addr
        v2f nxA = xA2[p0 + j + 2], nxB = xB2[p0 + j + 2];
        CMat C;
        build_C(C, s, xA);  matmulIP(MA, C);
        build_C(C, s, xB);  matmulIP(MB, C);   // same SGPR quads
        xA = nxA; xB = nxB;
    }
}

// in-place M = M @ S  (S = 5x5 in matbuf slot; row i dep only on row i)
__device__ __forceinline__ void foldM(Frag& M, const float (*mb)[128], int ln) {
#pragma unroll
    for (int i = 0; i < 5; ++i) {
        float v[5];
#pragma unroll
        for (int r = 0; r < 5; ++r) {
            float a = M.r[i][0] * mb[r][ln];
#pragma unroll
            for (int l = 1; l < 4; ++l) a = fmaf(M.r[i][l], mb[l * 5 + r][ln], a);
            a = fmaf(M.c4[i], mb[20 + r][ln], a);
            v[r] = a;
        }
        M.r[i] = {v[0], v[1], v[2], v[3]}; M.c4[i] = v[4];
    }
}

// ---- prepack: build pair blocks (transposed for p >= bwd0) ----
__global__ void prepack_pairs(const float* __restrict__ cm, float* __restrict__ pk,
                              int bwd0)
{
    int idx = blockIdx.x * 256 + threadIdx.x;
    if (idx >= NPAIR * 100) return;
    int p = idx / 100, rest = idx - p * 100;
    int q = rest / 25, e = rest - q * 25;
    int l = e / 5, r = e - l * 5;
    int m1 = 2 * p + 1, m2 = 2 * p + 2;
    const float* L = cm + (size_t)(m1 * 5 + l) * 10;
    float acc = 0.f;
#pragma unroll
    for (int k = 0; k < 5; ++k) {
        float Lk = (q & 1) ? (L[5 + k] - L[k]) : L[k];
        const float* R = cm + (size_t)(m2 * 5 + k) * 10;
        float Rk = (q & 2) ? (R[5 + r] - R[r]) : R[r];
        acc = fmaf(Lk, Rk, acc);
    }
    int wl = l, wr = r;
    if (p >= bwd0) { wl = r; wr = l; }
    int off;
    if (wr < 4)      off = q * 20 + wl * 4 + wr;
    else if (wl < 4) off = 80 + wl * 4 + q;
    else             off = 96 + q;
    pk[(size_t)p * PAIR_F + off] = acc;
}

// ================= QUARTER-SPLIT PATH (needs ws >= 3.44 MB) =================

__global__ __launch_bounds__(512, 2)
void mps_quarter_kernel(const float* __restrict__ x,
                        const float* __restrict__ core_first,
                        const float* __restrict__ cores_mid,
                        const float* __restrict__ core_last,
                        float* __restrict__ ws,            // pk + M stash
                        float* __restrict__ out)           // vL/wR stash
{
    __shared__ float matbuf[4][25][128];  // 51.2 KB

    const float* __restrict__ pk = ws;
    const int lane = threadIdx.x & 63;
    const int wave = threadIdx.x >> 6;    // 0..7
    const int wu   = __builtin_amdgcn_readfirstlane(wave);
    const int g    = blockIdx.x >> 2;
    const int seg  = blockIdx.x & 3;
    const int rowA = g * 128 + lane;
    const int rowB = rowA + 64;
    const v2f* __restrict__ xA2 = (const v2f*)(x + (size_t)rowA * Dn);
    const v2f* __restrict__ xB2 = (const v2f*)(x + (size_t)rowB * Dn);

    if (wu >= 1) {
        // ---- matrix wave: 12 pairs, dual-row ----
        const int m0 = (seg == 0) ? 13 : (seg == 1) ? 111 : (seg == 2) ? 209 : 293;
        const int p0 = m0 + 12 * (wu - 1);

        Frag MA, MB;
        MA.r[0] = {1,0,0,0}; MA.r[1] = {0,1,0,0}; MA.r[2] = {0,0,1,0};
        MA.r[3] = {0,0,0,1}; MA.r[4] = {0,0,0,0};
        MA.c4[0] = 0; MA.c4[1] = 0; MA.c4[2] = 0; MA.c4[3] = 0; MA.c4[4] = 1;
        MB = MA;

        mat_chain(MA, MB, p0, 12, pk, xA2, xB2);

        const int ord  = (seg == 3) ? (7 - wu) : (wu - 1);
        const bool ph1 = (ord < 4);
        const int  k   = ph1 ? ord : ord - 4;
        if (ph1) {
#pragma unroll
            for (int i = 0; i < 5; ++i) {
#pragma unroll
                for (int r = 0; r < 4; ++r) {
                    matbuf[k][i * 5 + r][lane]      = MA.r[i][r];
                    matbuf[k][i * 5 + r][lane + 64] = MB.r[i][r];
                }
                matbuf[k][i * 5 + 4][lane]      = MA.c4[i];
                matbuf[k][i * 5 + 4][lane + 64] = MB.c4[i];
            }
        }
        __syncthreads();   // b1
        __syncthreads();   // b2
        if (!ph1) {
#pragma unroll
            for (int i = 0; i < 5; ++i) {
#pragma unroll
                for (int r = 0; r < 4; ++r) {
                    matbuf[k][i * 5 + r][lane]      = MA.r[i][r];
                    matbuf[k][i * 5 + r][lane + 64] = MB.r[i][r];
                }
                matbuf[k][i * 5 + 4][lane]      = MA.c4[i];
                matbuf[k][i * 5 + 4][lane + 64] = MB.c4[i];
            }
        }
        __syncthreads();   // b3
    } else if (seg == 0) {
        // ---- wave0 seg0: left boundary + pairs 0..12, fold asc -> vL ----
        v2f xA01 = xA2[0], xB01 = xB2[0];
        float clA[5], clB[5], cnA[5], cnB[5];
#pragma unroll
        for (int r = 0; r < 5; ++r) {
            float d = core_first[5 + r] - core_first[r];
            clA[r] = fmaf(xA01[0], d, core_first[r]);
            clB[r] = fmaf(xB01[0], d, core_first[r]);
        }
        const float* cm0 = cores_mid;
#pragma unroll
        for (int r = 0; r < 5; ++r) {
            float aA = 0.f, aB = 0.f;
#pragma unroll
            for (int l = 0; l < 5; ++l) {
                float base = cm0[l * 10 + r], d = cm0[l * 10 + 5 + r] - base;
                aA = fmaf(clA[l], fmaf(xA01[1], d, base), aA);
                aB = fmaf(clB[l], fmaf(xB01[1], d, base), aB);
            }
            cnA[r] = aA; cnB[r] = aB;
        }
        v4f cvA = {cnA[0], cnA[1], cnA[2], cnA[3]};
        v4f cvB = {cnB[0], cnB[1], cnB[2], cnB[3]};
        float c4A = cnA[4], c4B = cnB[4];

        v2f xA = xA2[1], xB = xB2[1];
#pragma unroll 1
        for (int p = 0; p < 13; ++p) {
            const float* s = pk + (size_t)p * PAIR_F;
            v2f nxA = xA2[p + 2], nxB = xB2[p + 2];
            CMat C;
            build_C(C, s, xA);  vecstepC(cvA, c4A, C);
            build_C(C, s, xB);  vecstepC(cvB, c4B, C);
            xA = nxA; xB = nxB;
        }
        clA[0] = cvA[0]; clA[1] = cvA[1]; clA[2] = cvA[2]; clA[3] = cvA[3]; clA[4] = c4A;
        clB[0] = cvB[0]; clB[1] = cvB[1]; clB[2] = cvB[2]; clB[3] = cvB[3]; clB[4] = c4B;

        __syncthreads();   // b1
#pragma unroll 1
        for (int k = 0; k < 4; ++k) {
            float vA[5], vB[5];
#pragma unroll
            for (int r = 0; r < 5; ++r) {
                vA[r] = clA[0] * matbuf[k][r][lane];
                vB[r] = clB[0] * matbuf[k][r][lane + 64];
            }
#pragma unroll
            for (int l = 1; l < 5; ++l)
#pragma unroll
                for (int r = 0; r < 5; ++r) {
                    vA[r] = fmaf(clA[l], matbuf[k][l * 5 + r][lane],      vA[r]);
                    vB[r] = fmaf(clB[l], matbuf[k][l * 5 + r][lane + 64], vB[r]);
                }
#pragma unroll
            for (int r = 0; r < 5; ++r) { clA[r] = vA[r]; clB[r] = vB[r]; }
        }
        __syncthreads();   // b2
        __syncthreads();   // b3
#pragma unroll 1
        for (int k = 0; k < 3; ++k) {
            float vA[5], vB[5];
#pragma unroll
            for (int r = 0; r < 5; ++r) {
                vA[r] = clA[0] * matbuf[k][r][lane];
                vB[r] = clB[0] * matbuf[k][r][lane + 64];
            }
#pragma unroll
            for (int l = 1; l < 5; ++l)
#pragma unroll
                for (int r = 0; r < 5; ++r) {
                    vA[r] = fmaf(clA[l], matbuf[k][l * 5 + r][lane],      vA[r]);
                    vB[r] = fmaf(clB[l], matbuf[k][l * 5 + r][lane + 64], vB[r]);
                }
#pragma unroll
            for (int r = 0; r < 5; ++r) { clA[r] = vA[r]; clB[r] = vB[r]; }
        }
        float* oA = out + (size_t)rowA * 5;
        float* oB = out + (size_t)rowB * 5;
#pragma unroll
        for (int i = 0; i < 5; ++i) { oA[i] = clA[i]; oB[i] = clB[i]; }
    } else if (seg == 3) {
        // ---- wave0 seg3: right boundary + pairs 389..377 desc, fold desc ----
        v2f xAz = xA2[391], xBz = xB2[391];
        float vlA[5], vlB[5], vnA[5], vnB[5];
#pragma unroll
        for (int l = 0; l < 5; ++l) {
            float base = core_last[2 * l], d = core_last[2 * l + 1] - base;
            vlA[l] = fmaf(xAz[1], d, base);
            vlB[l] = fmaf(xBz[1], d, base);
        }
        const float* cmL = cores_mid + (size_t)781 * 50;
#pragma unroll
        for (int l = 0; l < 5; ++l) {
            float aA = 0.f, aB = 0.f;
#pragma unroll
            for (int r = 0; r < 5; ++r) {
                float base = cmL[l * 10 + r], d = cmL[l * 10 + 5 + r] - base;
                aA = fmaf(fmaf(xAz[0], d, base), vlA[r], aA);
                aB = fmaf(fmaf(xBz[0], d, base), vlB[r], aB);
            }
            vnA[l] = aA; vnB[l] = aB;
        }
        v4f cvA = {vnA[0], vnA[1], vnA[2], vnA[3]};
        v4f cvB = {vnB[0], vnB[1], vnB[2], vnB[3]};
        float c4A = vnA[4], c4B = vnB[4];

        v2f xA = xA2[390], xB = xB2[390];
#pragma unroll 1
        for (int p = 389; p >= 377; --p) {                 // transposed storage
            const float* s = pk + (size_t)p * PAIR_F;
            v2f nxA = xA2[p], nxB = xB2[p];
            CMat C;
            build_C(C, s, xA);  vecstepC(cvA, c4A, C);
            build_C(C, s, xB);  vecstepC(cvB, c4B, C);
            xA = nxA; xB = nxB;
        }
        float uA[5] = {cvA[0], cvA[1], cvA[2], cvA[3], c4A};
        float uB[5] = {cvB[0], cvB[1], cvB[2], cvB[3], c4B};

        __syncthreads();   // b1: slots wu=7..4 at k=0..3
#pragma unroll 1
        for (int k = 0; k < 4; ++k) {                      // u = M_slot @ u
            float vA[5], vB[5];
#pragma unroll
            for (int i = 0; i < 5; ++i) {
                float aA = matbuf[k][i * 5][lane]      * uA[0];
                float aB = matbuf[k][i * 5][lane + 64] * uB[0];
#pragma unroll
                for (int l = 1; l < 5; ++l) {
                    aA = fmaf(matbuf[k][i * 5 + l][lane],      uA[l], aA);
                    aB = fmaf(matbuf[k][i * 5 + l][lane + 64], uB[l], aB);
                }
                vA[i] = aA; vB[i] = aB;
            }
#pragma unroll
            for (int i = 0; i < 5; ++i) { uA[i] = vA[i]; uB[i] = vB[i]; }
        }
        __syncthreads();   // b2
        __syncthreads();   // b3: slots wu=3..1 at k=0..2
#pragma unroll 1
        for (int k = 0; k < 3; ++k) {
            float vA[5], vB[5];
#pragma unroll
            for (int i = 0; i < 5; ++i) {
                float aA = matbuf[k][i * 5][lane]      * uA[0];
                float aB = matbuf[k][i * 5][lane + 64] * uB[0];
#pragma unroll
                for (int l = 1; l < 5; ++l) {
                    aA = fmaf(matbuf[k][i * 5 + l][lane],      uA[l], aA);
                    aB = fmaf(matbuf[k][i * 5 + l][lane + 64], uB[l], aB);
                }
                vA[i] = aA; vB[i] = aB;
            }
#pragma unroll
            for (int i = 0; i < 5; ++i) { uA[i] = vA[i]; uB[i] = vB[i]; }
        }
        float* oA = out + WROFF + (size_t)rowA * 5;
        float* oB = out + WROFF + (size_t)rowB * 5;
#pragma unroll
        for (int i = 0; i < 5; ++i) { oA[i] = uA[i]; oB[i] = uB[i]; }
    } else {
        // ---- wave0 seg1/2: own 14-pair chain + in-place fold asc -> M stash ----
        const int p0 = (seg == 1) ? 97 : 195;

        Frag MA, MB;
        MA.r[0] = {1,0,0,0}; MA.r[1] = {0,1,0,0}; MA.r[2] = {0,0,1,0};
        MA.r[3] = {0,0,0,1}; MA.r[4] = {0,0,0,0};
        MA.c4[0] = 0; MA.c4[1] = 0; MA.c4[2] = 0; MA.c4[3] = 0; MA.c4[4] = 1;
        MB = MA;

        mat_chain(MA, MB, p0, 14, pk, xA2, xB2);

        __syncthreads();   // b1: slots wu=1..4 at k=0..3
#pragma unroll 1
        for (int k = 0; k < 4; ++k) {
            foldM(MA, matbuf[k], lane);
            foldM(MB, matbuf[k], lane + 64);
        }
        __syncthreads();   // b2
        __syncthreads();   // b3: slots wu=5..7 at k=0..2
#pragma unroll 1
        for (int k = 0; k < 3; ++k) {
            foldM(MA, matbuf[k], lane);
            foldM(MB, matbuf[k], lane + 64);
        }
        float* mA = ws + M_OFF + ((size_t)(seg - 1) * Bn + rowA) * 25;
        float* mB = ws + M_OFF + ((size_t)(seg - 1) * Bn + rowB) * 25;
#pragma unroll
        for (int i = 0; i < 5; ++i) {
#pragma unroll
            for (int r = 0; r < 4; ++r) {
                mA[i * 5 + r] = MA.r[i][r];
                mB[i * 5 + r] = MB.r[i][r];
            }
            mA[i * 5 + 4] = MA.c4[i];
            mB[i * 5 + 4] = MB.c4[i];
        }
    }
}

// res = (vL @ M1 @ M2) . wR  -> ws[0..Bn)  (pk dead)
__global__ __launch_bounds__(256)
void finish_dot_q(const float* __restrict__ outF, float* __restrict__ ws)
{
    int row = blockIdx.x * 256 + threadIdx.x;
    const float* vl = outF + (size_t)row * 5;
    const float* wr = outF + WROFF + (size_t)row * 5;
    const float* M1 = ws + M_OFF + (size_t)row * 25;
    const float* M2 = ws + M_OFF + ((size_t)Bn + row) * 25;
    float t[5], v[5];
#pragma unroll
    for (int r = 0; r < 5; ++r) {
        float a = vl[0] * M1[r];
#pragma unroll
        for (int l = 1; l < 5; ++l) a = fmaf(vl[l], M1[l * 5 + r], a);
        t[r] = a;
    }
#pragma unroll
    for (int r = 0; r < 5; ++r) {
        float a = t[0] * M2[r];
#pragma unroll
        for (int l = 1; l < 5; ++l) a = fmaf(t[l], M2[l * 5 + r], a);
        v[r] = a;
    }
    float res = v[0] * wr[0];
#pragma unroll
    for (int i = 1; i < 5; ++i) res = fmaf(v[i], wr[i], res);
    ws[row] = res;
}

// ================= HALF-SPLIT FALLBACK (r12, proven; ws = 156 KB) =========

__global__ __launch_bounds__(512, 2)
void mps_half_kernel(const float* __restrict__ x,
                     const float* __restrict__ core_first,
                     const float* __restrict__ cores_mid,
                     const float* __restrict__ core_last,
                     const float* __restrict__ pk,
                     float* __restrict__ out)
{
    __shared__ float matbuf[4][25][128];

    const int lane = threadIdx.x & 63;
    const int wave = threadIdx.x >> 6;
    const int wu   = __builtin_amdgcn_readfirstlane(wave);
    const int g    = blockIdx.x >> 1;
    const int h    = blockIdx.x & 1;
    const int rowA = g * 128 + lane;
    const int rowB = rowA + 64;
    const v2f* __restrict__ xA2 = (const v2f*)(x + (size_t)rowA * Dn);
    const v2f* __restrict__ xB2 = (const v2f*)(x + (size_t)rowB * Dn);

    if (wu >= 1) {
        const int p0 = (h == 0 ? 20 : 195) + 25 * (wu - 1);
        Frag MA, MB;
        MA.r[0] = {1,0,0,0}; MA.r[1] = {0,1,0,0}; MA.r[2] = {0,0,1,0};
        MA.r[3] = {0,0,0,1}; MA.r[4] = {0,0,0,0};
        MA.c4[0] = 0; MA.c4[1] = 0; MA.c4[2] = 0; MA.c4[3] = 0; MA.c4[4] = 1;
        MB = MA;
        mat_chain(MA, MB, p0, 25, pk, xA2, xB2);

        const int ord  = (h == 0) ? (wu - 1) : (7 - wu);
        const bool ph1 = (ord < 4);
        const int  k   = ph1 ? ord : ord - 4;
        if (ph1) {
#pragma unroll
            for (int i = 0; i < 5; ++i) {
#pragma unroll
                for (int r = 0; r < 4; ++r) {
                    matbuf[k][i * 5 + r][lane]      = MA.r[i][r];
                    matbuf[k][i * 5 + r][lane + 64] = MB.r[i][r];
                }
                matbuf[k][i * 5 + 4][lane]      = MA.c4[i];
                matbuf[k][i * 5 + 4][lane + 64] = MB.c4[i];
            }
        }
        __syncthreads();
        __syncthreads();
        if (!ph1) {
#pragma unroll
            for (int i = 0; i < 5; ++i) {
#pragma unroll
                for (int r = 0; r < 4; ++r) {
                    matbuf[k][i * 5 + r][lane]      = MA.r[i][r];
                    matbuf[k][i * 5 + r][lane + 64] = MB.r[i][r];
                }
                matbuf[k][i * 5 + 4][lane]      = MA.c4[i];
                matbuf[k][i * 5 + 4][lane + 64] = MB.c4[i];
            }
        }
        __syncthreads();
    } else if (h == 0) {
        v2f xA01 = xA2[0], xB01 = xB2[0];
        float clA[5], clB[5], cnA[5], cnB[5];
#pragma unroll
        for (int r = 0; r < 5; ++r) {
            float d = core_first[5 + r] - core_first[r];
            clA[r] = fmaf(xA01[0], d, core_first[r]);
            clB[r] = fmaf(xB01[0], d, core_first[r]);
        }
        const float* cm0 = cores_mid;
#pragma unroll
        for (int r = 0; r < 5; ++r) {
            float aA = 0.f, aB = 0.f;
#pragma unroll
            for (int l = 0; l < 5; ++l) {
                float base = cm0[l * 10 + r], d = cm0[l * 10 + 5 + r] - base;
                aA = fmaf(clA[l], fmaf(xA01[1], d, base), aA);
                aB = fmaf(clB[l], fmaf(xB01[1], d, base), aB);
            }
            cnA[r] = aA; cnB[r] = aB;
        }
        v4f cvA = {cnA[0], cnA[1], cnA[2], cnA[3]};
        v4f cvB = {cnB[0], cnB[1], cnB[2], cnB[3]};
        float c4A = cnA[4], c4B = cnB[4];

        v2f xA = xA2[1], xB = xB2[1];
#pragma unroll 1
        for (int p = 0; p < 20; ++p) {
            const float* s = pk + (size_t)p * PAIR_F;
            v2f nxA = xA2[p + 2], nxB = xB2[p + 2];
            CMat C;
            build_C(C, s, xA);  vecstepC(cvA, c4A, C);
            build_C(C, s, xB);  vecstepC(cvB, c4B, C);
            xA = nxA; xB = nxB;
        }
        clA[0] = cvA[0]; clA[1] = cvA[1]; clA[2] = cvA[2]; clA[3] = cvA[3]; clA[4] = c4A;
        clB[0] = cvB[0]; clB[1] = cvB[1]; clB[2] = cvB[2]; clB[3] = cvB[3]; clB[4] = c4B;

        __syncthreads();
#pragma unroll 1
        for (int k = 0; k < 4; ++k) {
            float vA[5], vB[5];
#pragma unroll
            for (int r = 0; r < 5; ++r) {
                vA[r] = clA[0] * matbuf[k][r][lane];
                vB[r] = clB[0] * matbuf[k][r][lane + 64];
            }
#pragma unroll
            for (int l = 1; l < 5; ++l)
#pragma unroll
                for (int r = 0; r < 5; ++r) {
                    vA[r] = fmaf(clA[l], matbuf[k][l * 5 + r][lane],      vA[r]);
                    vB[r] = fmaf(clB[l], matbuf[k][l * 5 + r][lane + 64], vB[r]);
                }
#pragma unroll
            for (int r = 0; r < 5; ++r) { clA[r] = vA[r]; clB[r] = vB[r]; }
        }
        __syncthreads();
        __syncthreads();
#pragma unroll 1
        for (int k = 0; k < 3; ++k) {
            float vA[5], vB[5];
#pragma unroll
            for (int r = 0; r < 5; ++r) {
                vA[r] = clA[0] * matbuf[k][r][lane];
                vB[r] = clB[0] * matbuf[k][r][lane + 64];
            }
#pragma unroll
            for (int l = 1; l < 5; ++l)
#pragma unroll
                for (int r = 0; r < 5; ++r) {
                    vA[r] = fmaf(clA[l], matbuf[k][l * 5 + r][lane],      vA[r]);
                    vB[r] = fmaf(clB[l], matbuf[k][l * 5 + r][lane + 64], vB[r]);
                }
#pragma unroll
            for (int r = 0; r < 5; ++r) { clA[r] = vA[r]; clB[r] = vB[r]; }
        }
        float* oA = out + (size_t)rowA * 5;
        float* oB = out + (size_t)rowB * 5;
#pragma unroll
        for (int i = 0; i < 5; ++i) { oA[i] = clA[i]; oB[i] = clB[i]; }
    } else {
        v2f xAz = xA2[391], xBz = xB2[391];
        float vlA[5], vlB[5], vnA[5], vnB[5];
#pragma unroll
        for (int l = 0; l < 5; ++l) {
            float base = core_last[2 * l], d = core_last[2 * l + 1] - base;
            vlA[l] = fmaf(xAz[1], d, base);
            vlB[l] = fmaf(xBz[1], d, base);
        }
        const float* cmL = cores_mid + (size_t)781 * 50;
#pragma unroll
        for (int l = 0; l < 5; ++l) {
            float aA = 0.f, aB = 0.f;
#pragma unroll
            for (int r = 0; r < 5; ++r) {
                float base = cmL[l * 10 + r], d = cmL[l * 10 + 5 + r] - base;
                aA = fmaf(fmaf(xAz[0], d, base), vlA[r], aA);
                aB = fmaf(fmaf(xBz[0], d, base), vlB[r], aB);
            }
            vnA[l] = aA; vnB[l] = aB;
        }
        v4f cvA = {vnA[0], vnA[1], vnA[2], vnA[3]};
        v4f cvB = {vnB[0], vnB[1], vnB[2], vnB[3]};
        float c4A = vnA[4], c4B = vnB[4];

        v2f xA = xA2[390], xB = xB2[390];
#pragma unroll 1
        for (int p = 389; p >= 370; --p) {
            const float* s = pk + (size_t)p * PAIR_F;
            v2f nxA = xA2[p], nxB = xB2[p];
            CMat C;
            build_C(C, s, xA);  vecstepC(cvA, c4A, C);
            build_C(C, s, xB);  vecstepC(cvB, c4B, C);
            xA = nxA; xB = nxB;
        }
        float uA[5] = {cvA[0], cvA[1], cvA[2], cvA[3], c4A};
        float uB[5] = {cvB[0], cvB[1], cvB[2], cvB[3], c4B};

        __syncthreads();
#pragma unroll 1
        for (int k = 0; k < 4; ++k) {
            float vA[5], vB[5];
#pragma unroll
            for (int i = 0; i < 5; ++i) {
                float aA = matbuf[k][i * 5][lane]      * uA[0];
                float aB = matbuf[k][i * 5][lane + 64] * uB[0];
#pragma unroll
                for (int l = 1; l < 5; ++l) {
                    aA = fmaf(matbuf[k][i * 5 + l][lane],      uA[l], aA);
                    aB = fmaf(matbuf[k][i * 5 + l][lane + 64], uB[l], aB);
                }
                vA[i] = aA; vB[i] = aB;
            }
#pragma unroll
            for (int i = 0; i < 5; ++i) { uA[i] = vA[i]; uB[i] = vB[i]; }
        }
        __syncthreads();
        __syncthreads();
#pragma unroll 1
        for (int k = 0; k < 3; ++k) {
            float vA[5], vB[5];
#pragma unroll
            for (int i = 0; i < 5; ++i) {
                float aA = matbuf[k][i * 5][lane]      * uA[0];
                float aB = matbuf[k][i * 5][lane + 64] * uB[0];
#pragma unroll
                for (int l = 1; l < 5; ++l) {
                    aA = fmaf(matbuf[k][i * 5 + l][lane],      uA[l], aA);
                    aB = fmaf(matbuf[k][i * 5 + l][lane + 64], uB[l], aB);
                }
                vA[i] = aA; vB[i] = aB;
            }
#pragma unroll
            for (int i = 0; i < 5; ++i) { uA[i] = vA[i]; uB[i] = vB[i]; }
        }
        float* oA = out + WROFF + (size_t)rowA * 5;
        float* oB = out + WROFF + (size_t)rowB * 5;
#pragma unroll
        for (int i = 0; i < 5; ++i) { oA[i] = uA[i]; oB[i] = uB[i]; }
    }
}

// res[r] = vL . wR (half path)
__global__ __launch_bounds__(256)
void finish_dot_h(const float* __restrict__ outF, float* __restrict__ res)
{
    int r = blockIdx.x * 256 + threadIdx.x;
    const float* vl = outF + (size_t)r * 5;
    const float* wr = outF + WROFF + (size_t)r * 5;
    float s = vl[0] * wr[0];
#pragma unroll
    for (int i = 1; i < 5; ++i) s = fmaf(vl[i], wr[i], s);
    res[r] = s;
}

// out = res*fc_w + fc_b  (shared)
__global__ __launch_bounds__(256)
void finish_out(const float* __restrict__ res, const float* __restrict__ fc_w,
                const float* __restrict__ fc_b, float* __restrict__ out)
{
    int r = blockIdx.x * 256 + threadIdx.x;
    float rv = res[r];
    float* o = out + (size_t)r * NOUT;
#pragma unroll
    for (int j = 0; j < NOUT; ++j) o[j] = fmaf(rv, fc_w[j], fc_b[j]);
}

extern "C" void kernel_launch(void* const* d_in, const int* in_sizes, int n_in,
                              void* d_out, int out_size, void* d_ws, size_t ws_size,
                              hipStream_t stream) {
    const float* x          = (const float*)d_in[0];
    const float* core_first = (const float*)d_in[1];
    const float* cores_mid  = (const float*)d_in[2];
    const float* core_last  = (const float*)d_in[3];
    const float* fc_w       = (const float*)d_in[4];
    const float* fc_b       = (const float*)d_in[5];
    float* out              = (float*)d_out;
    float* ws               = (float*)d_ws;

    const size_t q_need = (size_t)(M_OFF + 2 * Bn * 25) * sizeof(float); // 3.44 MB

    if (ws_size >= q_need) {
        hipLaunchKernelGGL(prepack_pairs, dim3((NPAIR * 100 + 255) / 256), dim3(256),
                           0, stream, cores_mid, ws, 377);
        hipLaunchKernelGGL(mps_quarter_kernel, dim3(512), dim3(512), 0, stream,
                           x, core_first, cores_mid, core_last, ws, out);
        hipLaunchKernelGGL(finish_dot_q, dim3(Bn / 256), dim3(256), 0, stream,
                           out, ws);
        hipLaunchKernelGGL(finish_out, dim3(Bn / 256), dim3(256), 0, stream,
                           ws, fc_w, fc_b, out);
    } else {
        hipLaunchKernelGGL(prepack_pairs, dim3((NPAIR * 100 + 255) / 256), dim3(256),
                           0, stream, cores_mid, ws, 370);
        hipLaunchKernelGGL(mps_half_kernel, dim3(256), dim3(512), 0, stream,
                           x, core_first, cores_mid, core_last, ws, out);
        hipLaunchKernelGGL(finish_dot_h, dim3(Bn / 256), dim3(256), 0, stream,
                           out, ws);
        hipLaunchKernelGGL(finish_out, dim3(Bn / 256), dim3(256), 0, stream,
                           ws, fc_w, fc_b, out);
    }
}

// Round 12
// 132.013 us; speedup vs baseline: 1.1247x; 1.1247x over previous
//
#include <hip/hip_runtime.h>

// MPS tensor-train classifier, B=16384, D=784, BOND=5, OUT=10.
//
// Round-15: balanced 8-segment split, in-block combine, 2 launches.
// Arithmetic: matrix pair ~2x vector pair (build_C ~45 instr common;
// matmul 95 vs vecstep 20). r9 (47us best) did 360/390 pairs as matrix ->
// VALU issue ~23.5us = measured VALUBusy(50%) x 47us; rest = lockstep
// stalls + stash/finish overhead. This round: maximize vector pairs (the
// two chain ends) and balance: 2 vec x 75 pairs (~10.5k cyc) vs 6 mat x
// 40 pairs (~11.2k cyc). Matrix pairs 360 -> 240. One block per 64-row
// group does the WHOLE chain -> in-block combine, ONE barrier, out written
// directly (no vL/wR stash, no finish kernels; launches 4 -> 2).
//   256 blocks x 512 thr, __launch_bounds__(512,2) (proven 68-92 VGPR,
//   spill-free). LDS = matbuf[6][25][64] + vbuf[5][64] = 39.7 KB.
//   wave0: site0 boundary + vector pairs 0..74 -> vL -> vbuf.
//   waves 1..6: 40-pair matrix chains (75..314), M -> matbuf[wu-1].
//   wave7: site781 boundary + pairs 389..315 desc (transposed storage,
//          bwd0=315) -> u; after barrier: u = M_k @ u for k=5..0;
//          res = vL.u; out[row] = res*fc_w + fc_b.
// Step functions = round-7's proven l-major forms (44 VGPR single-row).
//
// pk layout (100 floats/pair), q = 0..3 (coeff of 1, xa, xb, xa*xb):
//   rows: q*20+l*4+r -> quad s4[q*5+l]; col4: 80+l*4+q -> s4[20+l]
//   (l-major); (4,4): 96+q -> s4[24].

typedef float v4f __attribute__((ext_vector_type(4)));
typedef float v2f __attribute__((ext_vector_type(2)));

constexpr int Bn     = 16384;
constexpr int Dn     = 784;
constexpr int NOUT   = 10;
constexpr int NPAIR  = 390;
constexpr int PAIR_F = 100;
constexpr int LV     = 75;    // vector pairs per end wave
constexpr int LM     = 40;    // matrix pairs per interior wave (x6)
constexpr int BWD0   = 315;   // pairs >= this stored transposed

__device__ __forceinline__ v4f splat4(float x) { v4f v = {x, x, x, x}; return v; }
__device__ __forceinline__ v4f fma4(v4f a, v4f b, v4f c) {
    return __builtin_elementwise_fma(a, b, c);
}

struct Frag { v4f r[5]; float c4[5]; };          // 5x5 running product

// T = M @ C(s; xa,xb), l-major: C row l built from uniform (SGPR)
// coefficients and immediately consumed (round-7 proven, 44 VGPR).
__device__ __forceinline__ void matstepLM(const Frag& M, Frag& T,
                                          const float* __restrict__ s, v2f xc) {
    const float xa = xc[0], xb = xc[1], xab = xa * xb;
    const v4f va = splat4(xa), vb = splat4(xb), vp = splat4(xab);
    const v4f* s4 = (const v4f*)s;
#pragma unroll
    for (int l = 0; l < 5; ++l) {
        v4f crow = fma4(vp, s4[15 + l], fma4(vb, s4[10 + l], fma4(va, s4[5 + l], s4[l])));
        v4f cq = (l < 4) ? s4[20 + l] : s4[24];
        float c4l = fmaf(xab, cq[3], fmaf(xb, cq[2], fmaf(xa, cq[1], cq[0])));
#pragma unroll
        for (int i = 0; i < 5; ++i) {
            float mil = (l < 4) ? M.r[i][l] : M.c4[i];
            if (l == 0) {
                T.r[i]  = splat4(mil) * crow;
                T.c4[i] = mil * c4l;
            } else {
                T.r[i]  = fma4(splat4(mil), crow, T.r[i]);
                T.c4[i] = fmaf(mil, c4l, T.c4[i]);
            }
        }
    }
}

// c' = c @ C (row vector), l-major (round-7 proven)
__device__ __forceinline__ void vecstepLM(v4f& cv, float& c4,
                                          const float* __restrict__ s, v2f xc) {
    const float xa = xc[0], xb = xc[1], xab = xa * xb;
    const v4f va = splat4(xa), vb = splat4(xb), vp = splat4(xab);
    const v4f* s4 = (const v4f*)s;
    v4f acc; float a4;
#pragma unroll
    for (int l = 0; l < 5; ++l) {
        v4f crow = fma4(vp, s4[15 + l], fma4(vb, s4[10 + l], fma4(va, s4[5 + l], s4[l])));
        v4f cq = (l < 4) ? s4[20 + l] : s4[24];
        float c4l = fmaf(xab, cq[3], fmaf(xb, cq[2], fmaf(xa, cq[1], cq[0])));
        float cl = (l < 4) ? cv[l] : c4;
        if (l == 0) { acc = splat4(cl) * crow; a4 = cl * c4l; }
        else        { acc = fma4(splat4(cl), crow, acc); a4 = fmaf(cl, c4l, a4); }
    }
    cv = acc; c4 = a4;
}

// ---- prepack: build pair blocks (transposed for p >= bwd0) ----
// cores_mid element (m,l,i,k) at (m*5+l)*10 + i*5 + k
__global__ void prepack_pairs(const float* __restrict__ cm, float* __restrict__ pk,
                              int bwd0)
{
    int idx = blockIdx.x * 256 + threadIdx.x;
    if (idx >= NPAIR * 100) return;
    int p = idx / 100, rest = idx - p * 100;
    int q = rest / 25, e = rest - q * 25;
    int l = e / 5, r = e - l * 5;
    int m1 = 2 * p + 1, m2 = 2 * p + 2;
    const float* L = cm + (size_t)(m1 * 5 + l) * 10;
    float acc = 0.f;
#pragma unroll
    for (int k = 0; k < 5; ++k) {
        float Lk = (q & 1) ? (L[5 + k] - L[k]) : L[k];
        const float* R = cm + (size_t)(m2 * 5 + k) * 10;
        float Rk = (q & 2) ? (R[5 + r] - R[r]) : R[r];
        acc = fmaf(Lk, Rk, acc);
    }
    int wl = l, wr = r;
    if (p >= bwd0) { wl = r; wr = l; }   // store C^T for bwd vec wave
    int off;
    if (wr < 4)      off = q * 20 + wl * 4 + wr;
    else if (wl < 4) off = 80 + wl * 4 + q;   // col4, l-major
    else             off = 96 + q;            // c44 quad
    pk[(size_t)p * PAIR_F + off] = acc;
}

__global__ __launch_bounds__(512, 2)
void mps_seg_kernel(const float* __restrict__ x,          // [B, D]
                    const float* __restrict__ core_first, // [2,5]
                    const float* __restrict__ cores_mid,  // [782,5,2,5]
                    const float* __restrict__ core_last,  // [5,2]
                    const float* __restrict__ fc_w,       // [10]
                    const float* __restrict__ fc_b,       // [10]
                    const float* __restrict__ pk,         // [390][100]
                    float* __restrict__ out)              // [B,10]
{
    __shared__ float matbuf[6][25][64];   // 38.4 KB segment matrices
    __shared__ float vbuf[5][64];         // vL

    const int lane = threadIdx.x & 63;
    const int wave = threadIdx.x >> 6;    // 0..7
    const int wu   = __builtin_amdgcn_readfirstlane(wave);
    const int row  = blockIdx.x * 64 + lane;
    const v2f* __restrict__ xr2 = (const v2f*)(x + (size_t)row * Dn);  // 392

    if (wu >= 1 && wu <= 6) {
        // ---- matrix wave: 40 pairs (even -> ping-pong ends in M) ----
        const int p0 = LV + LM * (wu - 1);                 // uniform

        Frag M, T;
        M.r[0] = {1,0,0,0}; M.r[1] = {0,1,0,0}; M.r[2] = {0,0,1,0};
        M.r[3] = {0,0,0,1}; M.r[4] = {0,0,0,0};
        M.c4[0] = 0; M.c4[1] = 0; M.c4[2] = 0; M.c4[3] = 0; M.c4[4] = 1;

        v2f x0 = xr2[p0 + 1], x1 = xr2[p0 + 2];
#pragma unroll 1
        for (int j = 0; j < LM; j += 2) {
            const float* s0 = pk + (size_t)(p0 + j) * PAIR_F;  // uniform addr
            v2f nx0 = xr2[p0 + j + 3], nx1 = xr2[p0 + j + 4];  // x prefetch
            matstepLM(M, T, s0, x0);
            matstepLM(T, M, s0 + PAIR_F, x1);
            x0 = nx0; x1 = nx1;
        }

        const int k = wu - 1;
#pragma unroll
        for (int i = 0; i < 5; ++i) {
#pragma unroll
            for (int r = 0; r < 4; ++r) matbuf[k][i * 5 + r][lane] = M.r[i][r];
            matbuf[k][i * 5 + 4][lane] = M.c4[i];
        }
        __syncthreads();
    } else if (wu == 0) {
        // ---- left vec wave: carry0, site 0, pairs 0..74 -> vbuf ----
        v2f x01 = xr2[0];
        float cl[5], cn[5];
#pragma unroll
        for (int r = 0; r < 5; ++r)
            cl[r] = fmaf(x01[0], core_first[5 + r] - core_first[r], core_first[r]);
        const float* cm0 = cores_mid;                      // site 0
#pragma unroll
        for (int r = 0; r < 5; ++r) {
            float a = 0.f;
#pragma unroll
            for (int l = 0; l < 5; ++l) {
                float m = fmaf(x01[1], cm0[l * 10 + 5 + r] - cm0[l * 10 + r], cm0[l * 10 + r]);
                a = fmaf(cl[l], m, a);
            }
            cn[r] = a;
        }
        v4f cv = {cn[0], cn[1], cn[2], cn[3]};
        float c4 = cn[4];

        v2f xc = xr2[1];
#pragma unroll 1
        for (int p = 0; p < LV; ++p) {
            v2f nx = xr2[p + 2];
            vecstepLM(cv, c4, pk + (size_t)p * PAIR_F, xc);
            xc = nx;
        }
        vbuf[0][lane] = cv[0]; vbuf[1][lane] = cv[1]; vbuf[2][lane] = cv[2];
        vbuf[3][lane] = cv[3]; vbuf[4][lane] = c4;
        __syncthreads();
    } else {
        // ---- right vec wave (wu==7): vlast, site 781, pairs 389..315 desc;
        //      after barrier: fold 6 matrices + final dot + out write ----
        v2f xz = xr2[391];                                 // {x782, x783}
        float vl[5], vn[5];
#pragma unroll
        for (int l = 0; l < 5; ++l)
            vl[l] = fmaf(xz[1], core_last[2 * l + 1] - core_last[2 * l], core_last[2 * l]);
        const float* cmL = cores_mid + (size_t)781 * 50;
#pragma unroll
        for (int l = 0; l < 5; ++l) {
            float a = 0.f;
#pragma unroll
            for (int r = 0; r < 5; ++r) {
                float m = fmaf(xz[0], cmL[l * 10 + 5 + r] - cmL[l * 10 + r], cmL[l * 10 + r]);
                a = fmaf(m, vl[r], a);
            }
            vn[l] = a;
        }
        v4f cv = {vn[0], vn[1], vn[2], vn[3]};
        float c4 = vn[4];

        v2f xc = xr2[390];
#pragma unroll 1
        for (int p = 389; p >= BWD0; --p) {                // transposed storage
            v2f nx = xr2[p];                               // x for pair p-1
            vecstepLM(cv, c4, pk + (size_t)p * PAIR_F, xc);
            xc = nx;
        }
        float u[5] = {cv[0], cv[1], cv[2], cv[3], c4};

        __syncthreads();   // matbuf + vbuf ready

#pragma unroll 1
        for (int k = 5; k >= 0; --k) {                     // u = M_k @ u
            float v0[5];
#pragma unroll
            for (int i = 0; i < 5; ++i) {
                float a = matbuf[k][i * 5][lane] * u[0];
#pragma unroll
                for (int l = 1; l < 5; ++l)
                    a = fmaf(matbuf[k][i * 5 + l][lane], u[l], a);
                v0[i] = a;
            }
#pragma unroll
            for (int i = 0; i < 5; ++i) u[i] = v0[i];
        }
        float res = 0.f;
#pragma unroll
        for (int l = 0; l < 5; ++l) res = fmaf(vbuf[l][lane], u[l], res);
        float* orow = out + (size_t)row * NOUT;
#pragma unroll
        for (int o = 0; o < NOUT; ++o) orow[o] = fmaf(res, fc_w[o], fc_b[o]);
    }
}

extern "C" void kernel_launch(void* const* d_in, const int* in_sizes, int n_in,
                              void* d_out, int out_size, void* d_ws, size_t ws_size,
                              hipStream_t stream) {
    const float* x          = (const float*)d_in[0];
    const float* core_first = (const float*)d_in[1];
    const float* cores_mid  = (const float*)d_in[2];
    const float* core_last  = (const float*)d_in[3];
    const float* fc_w       = (const float*)d_in[4];
    const float* fc_b       = (const float*)d_in[5];
    float* out              = (float*)d_out;
    float* pk               = (float*)d_ws;   // 390*100*4 = 156,000 B

    hipLaunchKernelGGL(prepack_pairs, dim3((NPAIR * 100 + 255) / 256), dim3(256),
                       0, stream, cores_mid, pk, BWD0);
    hipLaunchKernelGGL(mps_seg_kernel, dim3(Bn / 64), dim3(512), 0, stream,
                       x, core_first, cores_mid, core_last, fc_w, fc_b, pk, out);
}